// Round 8
// baseline (230.634 us; speedup 1.0000x reference)
//
#include <hip/hip_runtime.h>
#include <stdint.h>

// Problem constants
#define B_ 64
#define T_ 512
#define D_ 1024
#define S_ 1024
#define U_ 10

typedef float f32x2 __attribute__((ext_vector_type(2)));
typedef float f32x4 __attribute__((ext_vector_type(4)));

// workspace layout (in floats)
static constexpr int WS_PMZ = 0;                      // [512][2]  per-block (m, Z)
static constexpr int WS_E   = 1024;                   // [64][512] raw e values
static constexpr int WS_PV  = 33792;                  // [512][1024] partial weighted sums
static constexpr int WS_C   = 33792 + 512 * 1024;     // [64][10]  c[u] per batch

// ---------------------------------------------------------------------------
// DPP helpers. NOTE: with row_shr prefix patterns the segment TOTAL lands in
// the HIGHEST lane of the segment (g==7 / lane 15 / lane 63), never lane 0.
// ---------------------------------------------------------------------------
template <int CTRL>
__device__ __forceinline__ float dpp_add(float x) {
    int yi = __builtin_amdgcn_update_dpp(0, __float_as_int(x), CTRL, 0xf, 0xf, true);
    return x + __int_as_float(yi);
}
template <int CTRL>
__device__ __forceinline__ float dpp_max(float x) {
    int yi = __builtin_amdgcn_update_dpp(0, __float_as_int(x), CTRL, 0xf, 0xf, true);
    return fmaxf(x, __int_as_float(yi));   // shifted-in 0 is identity: e >= 0 (relu)
}

__device__ __forceinline__ float wave_sum63(float x) {   // full 64-lane (k0 only)
    x = dpp_add<0x111>(x);
    x = dpp_add<0x112>(x);
    x = dpp_add<0x114>(x);
    x = dpp_add<0x118>(x);
    x = dpp_add<0x142>(x);
    x = dpp_add<0x143>(x);
    return x;   // lane 63 = total
}

__device__ __forceinline__ float rdlane15(float x) {   // row-prefix total lane
    return __int_as_float(__builtin_amdgcn_readlane(__float_as_int(x), 15));
}
__device__ __forceinline__ float uload(const float* p) {
    return __int_as_float(__builtin_amdgcn_readfirstlane(__float_as_int(*p)));
}

__device__ __forceinline__ f32x2 pk_fma(f32x2 a, f32x2 b, f32x2 c) {
#if __has_builtin(__builtin_elementwise_fma)
    return __builtin_elementwise_fma(a, b, c);
#else
    return a * b + c;
#endif
}

// ---------------------------------------------------------------------------
// K0: c[b][u] = s_prev[b]·W1[D:,u] + b1[u]   (64 blocks x 256 threads)
// ---------------------------------------------------------------------------
__global__ __launch_bounds__(256) void k0_prep(const float* __restrict__ s_prev,
                                               const float* __restrict__ W1,
                                               const float* __restrict__ b1,
                                               float* __restrict__ ws) {
    const int b    = blockIdx.x;
    const int tid  = threadIdx.x;
    const int wave = tid >> 6;
    const int lane = tid & 63;

    f32x2 acc2[5];
#pragma unroll
    for (int h = 0; h < 5; h++) acc2[h] = f32x2{0.f, 0.f};

    const f32x4 s4 = *(const f32x4*)(s_prev + b * S_ + tid * 4);
    const float sv[4] = {s4.x, s4.y, s4.z, s4.w};
#pragma unroll
    for (int i = 0; i < 4; i++) {
        const float* wp = W1 + (size_t)(D_ + tid * 4 + i) * U_;
        const f32x2 svv = f32x2{sv[i], sv[i]};
#pragma unroll
        for (int h = 0; h < 5; h++)
            acc2[h] = pk_fma(svv, *(const f32x2*)(wp + 2 * h), acc2[h]);
    }

    __shared__ float red[4][U_];
    const float vals[U_] = {acc2[0].x, acc2[0].y, acc2[1].x, acc2[1].y, acc2[2].x,
                            acc2[2].y, acc2[3].x, acc2[3].y, acc2[4].x, acc2[4].y};
#pragma unroll
    for (int u = 0; u < U_; u++) {
        float s = wave_sum63(vals[u]);
        if (lane == 63) red[wave][u] = s;
    }
    __syncthreads();
    if (tid < U_)
        ws[WS_C + b * U_ + tid] =
            red[0][tid] + red[1][tid] + red[2][tid] + red[3][tid] + b1[tid];
}

// ---------------------------------------------------------------------------
// K1: 512 blocks (64 b x 8 chunks of 64 t) x 4 waves; wave owns 16 t.
// 8x8 lane layout: lane = (tt = lane>>3, g = lane&7) owns t in {tt, tt+8}
// and d-slice [g*128, g*128+128). Per W1 LDS read, TWO t's are advanced.
//  - per-(t,u) reduce = 3-step row_shr prefix over 8 g-lanes; group total
//    lands in g==7 (FIXED from round 6's g==0).
//  - W1[:D] in LDS (41 KB) with +2g bank skew: 8 g-groups hit 8 distinct
//    banks, broadcast within each group.
//  - a-loads are plain register loads, 4-deep rotation.
//  - exact per-wave softmax over 16 t (row-prefix totals read from lane 15 —
//    FIXED from round 6's lane 0); weighted sum re-reads tile from L2/L3.
// ---------------------------------------------------------------------------
__global__ __launch_bounds__(256, 2) void k1_main(const float* __restrict__ a,
                                                  const float* __restrict__ W1,
                                                  const float* __restrict__ W2,
                                                  const float* __restrict__ b2,
                                                  float* __restrict__ ws) {
    const int blk  = blockIdx.x;
    const int b    = blk >> 3;
    const int p    = blk & 7;
    const int tid  = threadIdx.x;
    const int wave = tid >> 6;
    const int lane = tid & 63;

    __shared__ __align__(16) float w1s[10256];   // W1[:D] skewed: F(d,u)=d*10+u+2*(d>>7)
    __shared__ float esh[4][16];
    __shared__ float wsh[4][16];
    __shared__ float mzs[4][2];

    // ---- stage W1[:D] -> LDS (each thread 4 d-rows) ----
#pragma unroll
    for (int r = 0; r < 4; r++) {
        const int d = r * 256 + tid;
        const float* wp = W1 + (size_t)d * U_;
        const int fb = d * U_ + 2 * (d >> 7);
#pragma unroll
        for (int h = 0; h < 5; h++)
            *(f32x2*)(&w1s[fb + 2 * h]) = *(const f32x2*)(wp + 2 * h);
    }

    // uniform constants (one-time)
    float c[U_], w2v[U_];
    {
        const float* cb = ws + WS_C + b * U_;
#pragma unroll
        for (int u = 0; u < U_; u++) c[u] = uload(cb + u);
#pragma unroll
        for (int u = 0; u < U_; u++) w2v[u] = uload(W2 + u);
    }
    const float b2s = uload(b2);
    __syncthreads();   // w1s ready

    const int tt = lane >> 3;
    const int g  = lane & 7;
    const int t0w = p * 64 + wave * 16;

    const float* aA = a + (size_t)(b * T_ + t0w + tt) * D_ + g * 128;
    const float* aB = aA + (size_t)8 * D_;
    const int wb = g * 1282;   // F(g*128, 0) = g*1280 + 2g

    // ---- dot phase: 32 chunks of 4 d, two t-rows per W1 read ----
    f32x2 accA[5], accB[5];
#pragma unroll
    for (int h = 0; h < 5; h++) { accA[h] = f32x2{0.f, 0.f}; accB[h] = f32x2{0.f, 0.f}; }

    f32x4 rA[4], rB[4];
#pragma unroll
    for (int q = 0; q < 4; q++) {
        rA[q] = *(const f32x4*)(aA + q * 4);
        rB[q] = *(const f32x4*)(aB + q * 4);
    }

#pragma unroll 1
    for (int j = 0; j < 32; j += 4) {
#pragma unroll
        for (int q = 0; q < 4; q++) {
            const f32x4 vA = rA[q], vB = rB[q];
            if (j + 4 + q < 32) {
                rA[q] = *(const f32x4*)(aA + (j + 4 + q) * 4);
                rB[q] = *(const f32x4*)(aB + (j + 4 + q) * 4);
            }
            const int fbase = wb + (j + q) * 40;
            const float aAv[4] = {vA.x, vA.y, vA.z, vA.w};
            const float aBv[4] = {vB.x, vB.y, vB.z, vB.w};
#pragma unroll
            for (int i = 0; i < 4; i++) {
                const f32x2* wp = (const f32x2*)&w1s[fbase + i * 10];
                const f32x2 va = f32x2{aAv[i], aAv[i]};
                const f32x2 vb = f32x2{aBv[i], aBv[i]};
#pragma unroll
                for (int h = 0; h < 5; h++) {
                    const f32x2 wv = wp[h];
                    accA[h] = pk_fma(va, wv, accA[h]);
                    accB[h] = pk_fma(vb, wv, accB[h]);
                }
            }
        }
    }

    // ---- 3-step 8-lane prefix reduce; group total lands in g==7 ----
    float xsA[U_] = {accA[0].x, accA[0].y, accA[1].x, accA[1].y, accA[2].x,
                     accA[2].y, accA[3].x, accA[3].y, accA[4].x, accA[4].y};
    float xsB[U_] = {accB[0].x, accB[0].y, accB[1].x, accB[1].y, accB[2].x,
                     accB[2].y, accB[3].x, accB[3].y, accB[4].x, accB[4].y};
#pragma unroll
    for (int u = 0; u < U_; u++) {
        xsA[u] = dpp_add<0x114>(dpp_add<0x112>(dpp_add<0x111>(xsA[u])));
        xsB[u] = dpp_add<0x114>(dpp_add<0x112>(dpp_add<0x111>(xsB[u])));
    }

    // ---- e for the two t's (8 lanes per wave, the g==7 ones) ----
    if (g == 7) {
        float eA = b2s, eB = b2s;
#pragma unroll
        for (int u = 0; u < U_; u++) {
            float xA = xsA[u] + c[u];
            float xB = xsB[u] + c[u];
            float exA = exp2f(xA * 2.8853900817779268f);
            float exB = exp2f(xB * 2.8853900817779268f);
            eA += (1.f - 2.f * __builtin_amdgcn_rcpf(exA + 1.f)) * w2v[u];
            eB += (1.f - 2.f * __builtin_amdgcn_rcpf(exB + 1.f)) * w2v[u];
        }
        eA = fmaxf(eA, 0.f);
        eB = fmaxf(eB, 0.f);
        esh[wave][tt]     = eA;
        esh[wave][tt + 8] = eB;
        ws[WS_E + b * T_ + t0w + tt]     = eA;
        ws[WS_E + b * T_ + t0w + tt + 8] = eB;
    }

    // ---- exact softmax over the wave's 16 t (row totals in lane 15) ----
    const float el = esh[wave][lane & 15];
    float mx = dpp_max<0x118>(dpp_max<0x114>(dpp_max<0x112>(dpp_max<0x111>(el))));
    const float m = rdlane15(mx);
    const float w_l = exp2f((el - m) * 1.4426950408889634f);
    float zt = dpp_add<0x118>(dpp_add<0x114>(dpp_add<0x112>(dpp_add<0x111>(w_l))));
    const float Z = rdlane15(zt);
    if (lane < 16) wsh[wave][lane] = w_l;
    if (lane == 0) { mzs[wave][0] = m; mzs[wave][1] = Z; }

    // ---- weighted sum: lane owns d = k*256 + lane*4; tile re-read (L2/L3) ----
    f32x2 v2[4][2];
#pragma unroll
    for (int k = 0; k < 4; k++) { v2[k][0] = f32x2{0.f, 0.f}; v2[k][1] = f32x2{0.f, 0.f}; }
    const float* abase = a + (size_t)(b * T_ + t0w) * D_ + lane * 4;
#pragma unroll 4
    for (int t = 0; t < 16; t++) {
        const float wt = wsh[wave][t];   // uniform broadcast
        const f32x2 wv = f32x2{wt, wt};
        const float* ar = abase + (size_t)t * D_;
#pragma unroll
        for (int k = 0; k < 4; k++) {
            const f32x4 av = *(const f32x4*)(ar + k * 256);
            v2[k][0] = pk_fma(wv, av.lo, v2[k][0]);
            v2[k][1] = pk_fma(wv, av.hi, v2[k][1]);
        }
    }

    // ---- block combine across 4 waves (vs4 aliases w1s after sync) ----
    __syncthreads();   // all w1s reads done
    f32x4* vs4 = (f32x4*)&w1s[0];   // [4][256] f32x4 = 16 KB
#pragma unroll
    for (int k = 0; k < 4; k++) {
        f32x4 o;
        o.lo = v2[k][0];
        o.hi = v2[k][1];
        vs4[wave * 256 + k * 64 + lane] = o;
    }
    __syncthreads();

    float m0 = mzs[0][0], m1 = mzs[1][0], m2 = mzs[2][0], m3 = mzs[3][0];
    float mb = fmaxf(fmaxf(m0, m1), fmaxf(m2, m3));
    float f0 = __expf(m0 - mb), f1 = __expf(m1 - mb);
    float f2 = __expf(m2 - mb), f3 = __expf(m3 - mb);
    float Zb = f0 * mzs[0][1] + f1 * mzs[1][1] + f2 * mzs[2][1] + f3 * mzs[3][1];

    f32x4 t0v = vs4[0 * 256 + tid], t1v = vs4[1 * 256 + tid];
    f32x4 t2v = vs4[2 * 256 + tid], t3v = vs4[3 * 256 + tid];
    f32x4 o = f0 * t0v + f1 * t1v + f2 * t2v + f3 * t3v;
    ((f32x4*)(ws + WS_PV))[blk * 256 + tid] = o;
    if (tid == 0) { ws[WS_PMZ + blk * 2] = mb; ws[WS_PMZ + blk * 2 + 1] = Zb; }
}

// ---------------------------------------------------------------------------
// K2: final combine per batch (8 partials) -> context + scores
// ---------------------------------------------------------------------------
__global__ __launch_bounds__(256) void k2_final(const float* __restrict__ ws,
                                                float* __restrict__ out) {
    const int b = blockIdx.x;
    const int tid = threadIdx.x;

    float pm[8], pz[8];
    float mb = -1e30f;
#pragma unroll
    for (int p = 0; p < 8; p++) {
        pm[p] = ws[WS_PMZ + (b * 8 + p) * 2];
        pz[p] = ws[WS_PMZ + (b * 8 + p) * 2 + 1];
        mb = fmaxf(mb, pm[p]);
    }
    float f[8], Z = 0.f;
#pragma unroll
    for (int p = 0; p < 8; p++) { f[p] = __expf(pm[p] - mb); Z += f[p] * pz[p]; }
    const float rz = 1.f / Z;

    f32x4 o = f32x4{0.f, 0.f, 0.f, 0.f};
#pragma unroll
    for (int p = 0; p < 8; p++) {
        f32x4 t = ((const f32x4*)(ws + WS_PV))[(b * 8 + p) * 256 + tid];
        o += f[p] * t;
    }
    o *= rz;
    ((f32x4*)out)[b * 256 + tid] = o;

    for (int t = tid; t < T_; t += 256) {
        out[B_ * D_ + b * T_ + t] = __expf(ws[WS_E + b * T_ + t] - mb) * rz;
    }
}

// ---------------------------------------------------------------------------
extern "C" void kernel_launch(void* const* d_in, const int* in_sizes, int n_in,
                              void* d_out, int out_size, void* d_ws, size_t ws_size,
                              hipStream_t stream) {
    const float* a      = (const float*)d_in[0];
    const float* s_prev = (const float*)d_in[1];
    const float* W1     = (const float*)d_in[2];
    const float* b1     = (const float*)d_in[3];
    const float* W2     = (const float*)d_in[4];
    const float* b2     = (const float*)d_in[5];
    float* out = (float*)d_out;
    float* ws  = (float*)d_ws;

    k0_prep<<<dim3(B_), dim3(256), 0, stream>>>(s_prev, W1, b1, ws);
    k1_main<<<dim3(B_ * 8), dim3(256), 0, stream>>>(a, W1, W2, b2, ws);
    k2_final<<<dim3(B_), dim3(256), 0, stream>>>(ws, out);
}